// Round 1
// baseline (406.386 us; speedup 1.0000x reference)
//
#include <hip/hip_runtime.h>
#include <hip/hip_bf16.h>
#include <stdint.h>

// Problem constants (B=32, T=512, C=16, F=256, O=256)
#define R_TOTAL 16384   // B*T rows
#define F_DIM 256
#define C_DIM 16
#define O_DIM 256
#define K_DIM 768       // 3*F

using bf16x8 = __attribute__((ext_vector_type(8))) short;
using f32x4  = __attribute__((ext_vector_type(4))) float;

// RNE float->bf16 (inputs are finite; no NaN path needed)
__device__ __forceinline__ unsigned short f2bf(float x) {
    union { float f; unsigned u; } a; a.f = x;
    unsigned r = a.u + 0x7FFFu + ((a.u >> 16) & 1u);
    return (unsigned short)(r >> 16);
}

__device__ __forceinline__ void gld_lds16(const unsigned short* g, unsigned short* l) {
    __builtin_amdgcn_global_load_lds(
        (const __attribute__((address_space(1))) void*)g,
        (__attribute__((address_space(3))) void*)l, 16, 0, 0);
}

// ---------------------------------------------------------------------------
// Kernel 1: per-row coefficient computation + child mixing.
// One wave (64 lanes) per row; 4 rows per 256-thread block.
// Writes A[row, 0:256]=bf16(nodes), [256:512]=bf16(mixed_r), [512:768]=bf16(mixed_l)
// ---------------------------------------------------------------------------
__global__ __launch_bounds__(256) void mix_kernel(
    const float* __restrict__ nodes,      // [R,256]
    const float* __restrict__ cv,         // [R,16,256]
    const int*   __restrict__ children,   // [R,16]
    unsigned short* __restrict__ Am)      // [R,768] bf16
{
    const int tid  = threadIdx.x;
    const int lane = tid & 63;
    const int rl   = tid >> 6;                 // wave index == local row
    const int row  = (blockIdx.x << 2) + rl;

    // --- coefficients (wave-uniform) ---
    int chv = 0;
    if (lane < C_DIM) chv = children[(size_t)row * C_DIM + lane];
    unsigned long long bal = __ballot(chv != 0);   // lanes>=16 contribute 0
    unsigned mask16 = (unsigned)(bal & 0xFFFFull);
    int ns = __popc(mask16);

    float c_r[C_DIM], c_l[C_DIM];
    if (ns == 1) {
        // reference: c_r = "singles" (0.5 on first child slot, UNmasked)
#pragma unroll
        for (int i = 0; i < C_DIM; ++i) {
            float m  = (float)((mask16 >> i) & 1u);
            float cr = (i == 0) ? 0.5f : 0.0f;
            c_r[i] = cr;
            c_l[i] = (1.0f - cr) * m;
        }
    } else {
        float inv = (ns > 1) ? 1.0f / (float)(ns - 1) : 0.0f;  // ns==0: all masks 0 anyway
#pragma unroll
        for (int i = 0; i < C_DIM; ++i) {
            float m  = (float)((mask16 >> i) & 1u);
            float cr = (float)i * m * inv;
            c_r[i] = cr;
            c_l[i] = (1.0f - cr) * m;
        }
    }

    // --- mixing: each lane owns 4 consecutive features via float4 ---
    const float4* cvp = (const float4*)(cv + (size_t)row * (C_DIM * F_DIM));
    float4 mr = make_float4(0.f, 0.f, 0.f, 0.f);
    float4 ml = make_float4(0.f, 0.f, 0.f, 0.f);
#pragma unroll
    for (int i = 0; i < C_DIM; ++i) {
        float4 v = cvp[i * 64 + lane];
        float cr = c_r[i], cl = c_l[i];
        mr.x = fmaf(v.x, cr, mr.x); mr.y = fmaf(v.y, cr, mr.y);
        mr.z = fmaf(v.z, cr, mr.z); mr.w = fmaf(v.w, cr, mr.w);
        ml.x = fmaf(v.x, cl, ml.x); ml.y = fmaf(v.y, cl, ml.y);
        ml.z = fmaf(v.z, cl, ml.z); ml.w = fmaf(v.w, cl, ml.w);
    }
    float4 mt = ((const float4*)(nodes + (size_t)row * F_DIM))[lane];

    ushort4 ut = { f2bf(mt.x), f2bf(mt.y), f2bf(mt.z), f2bf(mt.w) };
    ushort4 ur = { f2bf(mr.x), f2bf(mr.y), f2bf(mr.z), f2bf(mr.w) };
    ushort4 ul = { f2bf(ml.x), f2bf(ml.y), f2bf(ml.z), f2bf(ml.w) };

    ushort4* arow = (ushort4*)(Am + (size_t)row * K_DIM);
    arow[lane]        = ut;   // k = 4*lane         (w_t block)
    arow[64 + lane]   = ur;   // k = 256 + 4*lane   (w_r block)
    arow[128 + lane]  = ul;   // k = 512 + 4*lane   (w_l block)
}

// ---------------------------------------------------------------------------
// Kernel 2: weights -> concatenated transposed bf16 Wt[n=256][k=768]
// k blocks: 0:w_t, 1:w_r, 2:w_l  (reference stacks [w_t, w_r, w_l])
// ---------------------------------------------------------------------------
__global__ __launch_bounds__(256) void wconv_kernel(
    const float* __restrict__ w_t, const float* __restrict__ w_l,
    const float* __restrict__ w_r, unsigned short* __restrict__ Wt)
{
    const int n = blockIdx.x;    // 0..255 output col
    const int t = threadIdx.x;   // 0..255 k within block
    unsigned short* dst = Wt + (size_t)n * K_DIM;
    dst[t]       = f2bf(w_t[(size_t)t * O_DIM + n]);
    dst[256 + t] = f2bf(w_r[(size_t)t * O_DIM + n]);
    dst[512 + t] = f2bf(w_l[(size_t)t * O_DIM + n]);
}

// ---------------------------------------------------------------------------
// Kernel 3: GEMM [16384,768] x [768,256] (Wt stored as [256,768] so B-frag
// loads like A-frag), bf16 MFMA 16x16x32, 128x128 block tile, 4 waves x 64x64.
// Epilogue: +conv, leaky_relu(0.01), fp32 out.
// ---------------------------------------------------------------------------
__global__ __launch_bounds__(256) void gemm_kernel(
    const unsigned short* __restrict__ Am,   // [16384,768] bf16
    const unsigned short* __restrict__ Wt,   // [256,768] bf16
    const float* __restrict__ conv,          // [256]
    float* __restrict__ out)                 // [16384,256]
{
    __shared__ unsigned short As[128 * 32];  // 8 KB
    __shared__ unsigned short Bs[128 * 32];  // 8 KB

    const int tid  = threadIdx.x;
    const int lane = tid & 63;
    const int wave = tid >> 6;
    const int m0 = blockIdx.y * 128;
    const int n0 = blockIdx.x * 128;
    const int wm = (wave >> 1) * 64;
    const int wn = (wave & 1) * 64;

    f32x4 acc[4][4] = {};

    const int lrow = lane >> 2;        // 0..15 within a 16-row staging group
    const int lcol = (lane & 3) * 8;   // k-element offset (8 bf16 = 16B)

    const unsigned short* gA0 = Am + (size_t)(m0 + lrow) * K_DIM + lcol;
    const unsigned short* gB0 = Wt + (size_t)(n0 + lrow) * K_DIM + lcol;

    for (int k0 = 0; k0 < K_DIM; k0 += 32) {
#pragma unroll
        for (int q = 0; q < 2; ++q) {
            const int rb = (wave * 2 + q) * 16;   // 16-row group this wave stages
            gld_lds16(gA0 + (size_t)rb * K_DIM + k0, &As[rb * 32]);
            gld_lds16(gB0 + (size_t)rb * K_DIM + k0, &Bs[rb * 32]);
        }
        __syncthreads();   // drains vmcnt for global_load_lds

        bf16x8 af[4], bfr[4];
        const int fr = lane & 15;
        const int fk = (lane >> 4) * 8;
#pragma unroll
        for (int mi = 0; mi < 4; ++mi)
            af[mi] = *(const bf16x8*)&As[(wm + mi * 16 + fr) * 32 + fk];
#pragma unroll
        for (int ni = 0; ni < 4; ++ni)
            bfr[ni] = *(const bf16x8*)&Bs[(wn + ni * 16 + fr) * 32 + fk];
#pragma unroll
        for (int mi = 0; mi < 4; ++mi)
#pragma unroll
            for (int ni = 0; ni < 4; ++ni)
                acc[mi][ni] = __builtin_amdgcn_mfma_f32_16x16x32_bf16(
                    af[mi], bfr[ni], acc[mi][ni], 0, 0, 0);
        __syncthreads();   // protect LDS reuse next iter
    }

    // Epilogue. C/D layout: col = lane&15, row = (lane>>4)*4 + reg  [m89/m91]
    const int cn    = lane & 15;
    const int rbase = (lane >> 4) * 4;
#pragma unroll
    for (int ni = 0; ni < 4; ++ni) {
        const int ncol = n0 + wn + ni * 16 + cn;
        const float cb = conv[ncol];
#pragma unroll
        for (int mi = 0; mi < 4; ++mi) {
            const int mrow = m0 + wm + mi * 16 + rbase;
            float* op = out + (size_t)mrow * O_DIM + ncol;
#pragma unroll
            for (int r = 0; r < 4; ++r) {
                float v = acc[mi][ni][r] + cb;
                op[(size_t)r * O_DIM] = (v > 0.0f) ? v : 0.01f * v;
            }
        }
    }
}

// ---------------------------------------------------------------------------
extern "C" void kernel_launch(void* const* d_in, const int* in_sizes, int n_in,
                              void* d_out, int out_size, void* d_ws, size_t ws_size,
                              hipStream_t stream) {
    // setup_inputs order: nodes, children_vectors, w_t, w_l, w_r, conv, children
    const float* nodes    = (const float*)d_in[0];
    const float* cv       = (const float*)d_in[1];
    const float* w_t      = (const float*)d_in[2];
    const float* w_l      = (const float*)d_in[3];
    const float* w_r      = (const float*)d_in[4];
    const float* conv     = (const float*)d_in[5];
    const int*   children = (const int*)d_in[6];
    float* out = (float*)d_out;

    // Workspace layout: A bf16 [16384*768] (24 MB) then Wt bf16 [256*768] (384 KB)
    unsigned short* Am = (unsigned short*)d_ws;
    unsigned short* Wt = Am + (size_t)R_TOTAL * K_DIM;

    mix_kernel<<<dim3(R_TOTAL / 4), dim3(256), 0, stream>>>(nodes, cv, children, Am);
    wconv_kernel<<<dim3(O_DIM), dim3(256), 0, stream>>>(w_t, w_l, w_r, Wt);
    gemm_kernel<<<dim3(2, 128), dim3(256), 0, stream>>>(Am, Wt, conv, out);
}

// Round 2
// 405.490 us; speedup vs baseline: 1.0022x; 1.0022x over previous
//
#include <hip/hip_runtime.h>
#include <hip/hip_bf16.h>
#include <stdint.h>

// Problem constants (B=32, T=512, C=16, F=256, O=256)
#define R_TOTAL 16384   // B*T rows
#define F_DIM 256
#define C_DIM 16
#define O_DIM 256
#define K_DIM 768       // 3*F
#define ROWS_PB 32      // rows per block (fused kernel)
#define MIX_STRIDE 784  // 768 + 16 pad (bf16 elements) -> A-frag reads at LDS floor

using bf16x8 = __attribute__((ext_vector_type(8))) short;
using f32x4  = __attribute__((ext_vector_type(4))) float;

// RNE float->bf16 (inputs finite; no NaN path needed)
__device__ __forceinline__ unsigned short f2bf(float x) {
    union { float f; unsigned u; } a; a.f = x;
    unsigned r = a.u + 0x7FFFu + ((a.u >> 16) & 1u);
    return (unsigned short)(r >> 16);
}

// ---------------------------------------------------------------------------
// Kernel 1: weights -> concatenated transposed bf16 Wt[n=256][k=768]
// k blocks: 0:w_t, 1:w_r, 2:w_l (reference stacks [w_t, w_r, w_l]).
// Tiny (384 KB out); stays L2-resident for the fused kernel's B-frag loads.
// ---------------------------------------------------------------------------
__global__ __launch_bounds__(256) void wconv_kernel(
    const float* __restrict__ w_t, const float* __restrict__ w_l,
    const float* __restrict__ w_r, unsigned short* __restrict__ Wt)
{
    const int n = blockIdx.x;    // 0..255 output col
    const int t = threadIdx.x;   // 0..255 k within a 256-block
    unsigned short* dst = Wt + (size_t)n * K_DIM;
    dst[t]       = f2bf(w_t[(size_t)t * O_DIM + n]);
    dst[256 + t] = f2bf(w_r[(size_t)t * O_DIM + n]);
    dst[512 + t] = f2bf(w_l[(size_t)t * O_DIM + n]);
}

// ---------------------------------------------------------------------------
// Kernel 2 (fused): per-row coefficients + child mixing -> LDS, then MFMA
// GEMM against L2-resident Wt, bias + leaky_relu epilogue.
// Block = 32 rows, 256 threads (4 waves). Wave w owns output cols [w*64,w*64+64).
// No barriers inside the K-loop (A in read-only LDS, B from global).
// ---------------------------------------------------------------------------
__global__ __launch_bounds__(256) void fused_kernel(
    const float* __restrict__ nodes,      // [R,256]
    const float* __restrict__ cv,         // [R,16,256]
    const int*   __restrict__ children,   // [R,16]
    const unsigned short* __restrict__ Wt,// [256,768] bf16
    const float* __restrict__ conv,       // [256]
    float* __restrict__ out)              // [R,256]
{
    __shared__ unsigned short mixed[ROWS_PB * MIX_STRIDE];  // ~49 KB
    __shared__ float cr_s[ROWS_PB][C_DIM];                  // 2 KB
    __shared__ float cl_s[ROWS_PB][C_DIM];                  // 2 KB

    const int tid  = threadIdx.x;
    const int lane = tid & 63;
    const int wave = tid >> 6;
    const int row0 = blockIdx.x * ROWS_PB;

    // --- coefficients: one thread per row (32 active threads) ---
    if (tid < ROWS_PB) {
        const int* chp = children + (size_t)(row0 + tid) * C_DIM;
        unsigned mask = 0;
#pragma unroll
        for (int i = 0; i < C_DIM; ++i)
            mask |= (chp[i] != 0) ? (1u << i) : 0u;
        const int ns = __popc(mask);
        if (ns == 1) {
            // reference "singles": c_r = 0.5 on first child slot, UNmasked
#pragma unroll
            for (int i = 0; i < C_DIM; ++i) {
                float m  = (float)((mask >> i) & 1u);
                float cr = (i == 0) ? 0.5f : 0.0f;
                cr_s[tid][i] = cr;
                cl_s[tid][i] = (1.0f - cr) * m;
            }
        } else {
            float inv = (ns > 1) ? 1.0f / (float)(ns - 1) : 0.0f;  // ns==0: masks all 0
#pragma unroll
            for (int i = 0; i < C_DIM; ++i) {
                float m  = (float)((mask >> i) & 1u);
                float cr = (float)i * m * inv;
                cr_s[tid][i] = cr;
                cl_s[tid][i] = (1.0f - cr) * m;
            }
        }
    }
    __syncthreads();

    // --- stage 1: mix children vectors -> mixed[32][768] bf16 in LDS ---
    // wave w handles rows w*8 .. w*8+7; each lane owns 4 consecutive features.
#pragma unroll
    for (int j = 0; j < ROWS_PB / 4 / 2; ++j) {   // 8/... -> 8 rows per wave
        // (ROWS_PB/4 waves' rows) -> loop count 8
    }
    for (int j = 0; j < 8; ++j) {
        const int lr  = wave * 8 + j;
        const int row = row0 + lr;
        float crr[C_DIM], cll[C_DIM];
#pragma unroll
        for (int i = 0; i < C_DIM; ++i) { crr[i] = cr_s[lr][i]; cll[i] = cl_s[lr][i]; }

        const float4* cvp = (const float4*)(cv + (size_t)row * (C_DIM * F_DIM));
        float4 mr = make_float4(0.f, 0.f, 0.f, 0.f);
        float4 ml = make_float4(0.f, 0.f, 0.f, 0.f);
#pragma unroll
        for (int i = 0; i < C_DIM; ++i) {
            float4 v = cvp[i * 64 + lane];
            float cr = crr[i], cl = cll[i];
            mr.x = fmaf(v.x, cr, mr.x); mr.y = fmaf(v.y, cr, mr.y);
            mr.z = fmaf(v.z, cr, mr.z); mr.w = fmaf(v.w, cr, mr.w);
            ml.x = fmaf(v.x, cl, ml.x); ml.y = fmaf(v.y, cl, ml.y);
            ml.z = fmaf(v.z, cl, ml.z); ml.w = fmaf(v.w, cl, ml.w);
        }
        float4 mt = ((const float4*)(nodes + (size_t)row * F_DIM))[lane];

        ushort4 ut = { f2bf(mt.x), f2bf(mt.y), f2bf(mt.z), f2bf(mt.w) };
        ushort4 ur = { f2bf(mr.x), f2bf(mr.y), f2bf(mr.z), f2bf(mr.w) };
        ushort4 ul = { f2bf(ml.x), f2bf(ml.y), f2bf(ml.z), f2bf(ml.w) };

        ushort4* mrow = (ushort4*)&mixed[lr * MIX_STRIDE];
        mrow[lane]       = ut;   // k = 4*lane          (w_t block)
        mrow[64 + lane]  = ur;   // k = 256 + 4*lane    (w_r block)
        mrow[128 + lane] = ul;   // k = 512 + 4*lane    (w_l block)
    }
    __syncthreads();

    // --- stage 2: GEMM [32 x 768] x Wt^T -> [32 x 256], wave w: cols w*64.. ---
    f32x4 acc[2][4] = {};
    const int fr  = lane & 15;          // frag row (A: m, B: n)
    const int fkd = (lane >> 4) * 8;    // frag k element offset
    const unsigned short* bptr = Wt + (size_t)(wave * 64 + fr) * K_DIM + fkd;
    const unsigned short* aptr = &mixed[fr * MIX_STRIDE + fkd];

    for (int k0 = 0; k0 < K_DIM; k0 += 32) {
        bf16x8 bfrag[4];
#pragma unroll
        for (int ni = 0; ni < 4; ++ni)
            bfrag[ni] = *(const bf16x8*)(bptr + (size_t)ni * 16 * K_DIM + k0);
        bf16x8 afrag[2];
#pragma unroll
        for (int mi = 0; mi < 2; ++mi)
            afrag[mi] = *(const bf16x8*)(aptr + mi * 16 * MIX_STRIDE + k0);
#pragma unroll
        for (int mi = 0; mi < 2; ++mi)
#pragma unroll
            for (int ni = 0; ni < 4; ++ni)
                acc[mi][ni] = __builtin_amdgcn_mfma_f32_16x16x32_bf16(
                    afrag[mi], bfrag[ni], acc[mi][ni], 0, 0, 0);
    }

    // --- epilogue: +conv, leaky_relu(0.01), fp32 out ---
    // C/D layout: col = lane&15, row = (lane>>4)*4 + reg   [m89/m91]
    const int cn    = lane & 15;
    const int rbase = (lane >> 4) * 4;
#pragma unroll
    for (int ni = 0; ni < 4; ++ni) {
        const int ncol = wave * 64 + ni * 16 + cn;
        const float cb = conv[ncol];
#pragma unroll
        for (int mi = 0; mi < 2; ++mi) {
            const int mrow = row0 + mi * 16 + rbase;
            float* op = out + (size_t)mrow * O_DIM + ncol;
#pragma unroll
            for (int r = 0; r < 4; ++r) {
                float v = acc[mi][ni][r] + cb;
                op[(size_t)r * O_DIM] = (v > 0.0f) ? v : 0.01f * v;
            }
        }
    }
}

// ---------------------------------------------------------------------------
extern "C" void kernel_launch(void* const* d_in, const int* in_sizes, int n_in,
                              void* d_out, int out_size, void* d_ws, size_t ws_size,
                              hipStream_t stream) {
    // setup_inputs order: nodes, children_vectors, w_t, w_l, w_r, conv, children
    const float* nodes    = (const float*)d_in[0];
    const float* cv       = (const float*)d_in[1];
    const float* w_t      = (const float*)d_in[2];
    const float* w_l      = (const float*)d_in[3];
    const float* w_r      = (const float*)d_in[4];
    const float* conv     = (const float*)d_in[5];
    const int*   children = (const int*)d_in[6];
    float* out = (float*)d_out;

    unsigned short* Wt = (unsigned short*)d_ws;   // 384 KB bf16

    wconv_kernel<<<dim3(O_DIM), dim3(256), 0, stream>>>(w_t, w_l, w_r, Wt);
    fused_kernel<<<dim3(R_TOTAL / ROWS_PB), dim3(256), 0, stream>>>(
        nodes, cv, children, Wt, conv, out);
}